// Round 2
// baseline (235.146 us; speedup 1.0000x reference)
//
#include <hip/hip_runtime.h>

// GAMSmooth: out[b,l,f] = (X_spline @ kernel)[idx[b,l], f] + bias[f]
// N_UNIQUE=10000, N_BASES=10, FILTERS=16, B=32, L=100000
// Memory-bound: 204.8 MB fp32 output write dominates.
//   kernel 1: tiny matmul+bias -> shrunk table in d_ws (640 KB, L2-resident)
//   kernel 2: gather; 4 threads/element, one float4 each (16 B), perfectly
//             coalesced stores. Stores/idx-loads are NONTEMPORAL so the
//             streaming 205 MB doesn't evict the 640 KB table from L2.

#define N_UNIQUE 10000
#define N_BASES  10
#define FILTERS  16

typedef float f32x4 __attribute__((ext_vector_type(4)));

__global__ __launch_bounds__(256) void gam_shrunk_kernel(
    const float* __restrict__ X, const float* __restrict__ K,
    const float* __restrict__ bias, float* __restrict__ shrunk) {
  __shared__ float sK[N_BASES * FILTERS];
  __shared__ float sB[FILTERS];
  int t = threadIdx.x;
  if (t < N_BASES * FILTERS) sK[t] = K[t];
  if (t < FILTERS) sB[t] = bias[t];
  __syncthreads();
  int u = blockIdx.x * 256 + t;
  if (u >= N_UNIQUE) return;

  float acc[FILTERS];
#pragma unroll
  for (int f = 0; f < FILTERS; ++f) acc[f] = sB[f];
#pragma unroll
  for (int b = 0; b < N_BASES; ++b) {
    float x = X[u * N_BASES + b];
#pragma unroll
    for (int f = 0; f < FILTERS; ++f) acc[f] += x * sK[b * FILTERS + f];
  }
  // Regular (cacheable) stores: we WANT the table resident in L2.
  f32x4* dst = (f32x4*)(shrunk + (size_t)u * FILTERS);
#pragma unroll
  for (int q = 0; q < 4; ++q) {
    f32x4 v = {acc[4 * q], acc[4 * q + 1], acc[4 * q + 2], acc[4 * q + 3]};
    dst[q] = v;
  }
}

// One float4 per thread; 4 consecutive threads cover one idx element's 16
// filters -> consecutive lanes store consecutive 16 B (perfect coalescing).
// Each 4-lane group reads one full 64 B table line (single cacheline).
__global__ __launch_bounds__(256) void gam_gather_kernel(
    const int* __restrict__ idx, const f32x4* __restrict__ shrunk4,
    f32x4* __restrict__ out4, int total4) {
  int gid = blockIdx.x * 256 + threadIdx.x;
  if (gid >= total4) return;
  int e = gid >> 2;                                // which (b,l) element
  int q = gid & 3;                                 // which float4 of the row
  int u = __builtin_nontemporal_load(idx + e);     // read-once stream: nt
  f32x4 v = shrunk4[(size_t)u * 4 + q];            // cacheable: L2-resident
  __builtin_nontemporal_store(v, out4 + gid);      // write-once stream: nt
}

extern "C" void kernel_launch(void* const* d_in, const int* in_sizes, int n_in,
                              void* d_out, int out_size, void* d_ws, size_t ws_size,
                              hipStream_t stream) {
  const int*   idx  = (const int*)d_in[0];    // [B, L]
  const float* X    = (const float*)d_in[1];  // [N_UNIQUE, N_BASES]
  const float* K    = (const float*)d_in[2];  // [N_BASES, FILTERS]
  const float* bias = (const float*)d_in[3];  // [FILTERS]
  float* out    = (float*)d_out;              // [B, L, FILTERS] fp32
  float* shrunk = (float*)d_ws;               // 10000*16 fp32 = 640 KB

  // Kernel 1: shrunk = X @ K + bias  (ws re-poisoned every launch -> must
  // rerun every call; ~5 us).
  gam_shrunk_kernel<<<(N_UNIQUE + 255) / 256, 256, 0, stream>>>(X, K, bias, shrunk);

  // Kernel 2: coalesced nontemporal gather.
  int n_elem = in_sizes[0];                   // B*L = 3,200,000
  long long total4ll = (long long)n_elem * 4; // 12,800,000 float4 stores
  int total4 = (int)total4ll;
  int blocks = (int)((total4ll + 255) / 256);
  gam_gather_kernel<<<blocks, 256, 0, stream>>>(idx, (const f32x4*)shrunk,
                                                (f32x4*)out, total4);
}